// Round 7
// baseline (373.050 us; speedup 1.0000x reference)
//
#include <hip/hip_runtime.h>

#define NUM_E 8
#define N_TOK 8192
#define DIM 1024

typedef __attribute__((ext_vector_type(8))) short short8;
typedef __attribute__((ext_vector_type(4))) float f32x4;

// fp32 -> bf16 round-to-nearest-even
__device__ __forceinline__ unsigned short f2bf(float f) {
  unsigned int u = __float_as_uint(f);
  u = (u + 0x7fffu + ((u >> 16) & 1u)) >> 16;
  return (unsigned short)u;
}

// async global->LDS, 16B per lane. Global addr is per-lane; LDS dest is
// wave-uniform base + lane*16 (m104/m108 semantics).
__device__ __forceinline__ void async16(const unsigned short* g, unsigned short* l) {
  __builtin_amdgcn_global_load_lds((const __attribute__((address_space(1))) void*)g,
                                   (__attribute__((address_space(3))) void*)l,
                                   16, 0, 0);
}

// ---------------- prep: fused W-transpose-convert + gating ----------------
__global__ __launch_bounds__(256) void prep_kernel(
    const float* __restrict__ W1, const float* __restrict__ W2,
    unsigned short* __restrict__ W1T, unsigned short* __restrict__ W2T,
    const float* __restrict__ x, const float* __restrict__ Wg,
    const float* __restrict__ bg, int* __restrict__ tok_top,
    float2* __restrict__ tok_wts, unsigned short* __restrict__ xb) {
  __shared__ float s[64][65];
  if (blockIdx.x < 4096) {
    // ---- W transpose-convert: W[e][k][n] fp32 -> WT[e][n][k] bf16 ----
    const int bx  = blockIdx.x;          // 16 mats * 16 ktiles * 16 ntiles
    const int mat = bx >> 8;
    const int tk  = (bx >> 4) & 15;
    const int tn  = bx & 15;
    const float* src;
    unsigned short* dst;
    if (mat < 8) { src = W1 + (size_t)mat * (DIM * DIM); dst = W1T + (size_t)mat * (DIM * DIM); }
    else         { src = W2 + (size_t)(mat - 8) * (DIM * DIM); dst = W2T + (size_t)(mat - 8) * (DIM * DIM); }
    const int k0 = tk * 64, n0 = tn * 64;
    const int t = threadIdx.x;
    const int nr = t & 63, wr = t >> 6;
#pragma unroll
    for (int i = 0; i < 16; ++i) {
      int k = i * 4 + wr;
      s[nr][k] = src[(size_t)(k0 + k) * DIM + n0 + nr];
    }
    __syncthreads();
    const int kq = (t & 15) * 4, nw = t >> 4;
#pragma unroll
    for (int i = 0; i < 4; ++i) {
      int n = i * 16 + nw;
      ushort4 o;
      o.x = f2bf(s[n][kq + 0]); o.y = f2bf(s[n][kq + 1]);
      o.z = f2bf(s[n][kq + 2]); o.w = f2bf(s[n][kq + 3]);
      *(ushort4*)(dst + (size_t)(n0 + n) * DIM + k0 + kq) = o;
    }
  } else {
    // ---- gating + x->bf16 conversion ----
    const int wave = threadIdx.x >> 6;
    const int lane = threadIdx.x & 63;
    const int n = (blockIdx.x - 4096) * 4 + wave;
    const float4* xr = (const float4*)(x + (size_t)n * DIM);
    unsigned short* xbr = xb + (size_t)n * DIM;
    float acc[NUM_E];
#pragma unroll
    for (int e = 0; e < NUM_E; ++e) acc[e] = 0.f;
#pragma unroll
    for (int it = 0; it < 4; ++it) {
      float4 xv = xr[it * 64 + lane];
      const float4* wr = (const float4*)Wg + (size_t)(it * 256 + lane * 4) * 2;
      float xs[4] = {xv.x, xv.y, xv.z, xv.w};
      union { unsigned short u[4]; uint2 v; } oo;
      oo.u[0] = f2bf(xv.x); oo.u[1] = f2bf(xv.y);
      oo.u[2] = f2bf(xv.z); oo.u[3] = f2bf(xv.w);
      *(uint2*)(xbr + it * 256 + lane * 4) = oo.v;
#pragma unroll
      for (int dd = 0; dd < 4; ++dd) {
        float4 wa = wr[dd * 2 + 0];
        float4 wb = wr[dd * 2 + 1];
        acc[0] += xs[dd] * wa.x; acc[1] += xs[dd] * wa.y;
        acc[2] += xs[dd] * wa.z; acc[3] += xs[dd] * wa.w;
        acc[4] += xs[dd] * wb.x; acc[5] += xs[dd] * wb.y;
        acc[6] += xs[dd] * wb.z; acc[7] += xs[dd] * wb.w;
      }
    }
#pragma unroll
    for (int e = 0; e < NUM_E; ++e)
#pragma unroll
      for (int off = 32; off > 0; off >>= 1)
        acc[e] += __shfl_down(acc[e], off);
    if (lane == 0) {
      float p[NUM_E];
      float mx = -1e30f;
#pragma unroll
      for (int e = 0; e < NUM_E; ++e) { p[e] = acc[e] + bg[e]; mx = fmaxf(mx, p[e]); }
      float ss = 0.f;
#pragma unroll
      for (int e = 0; e < NUM_E; ++e) { p[e] = expf(p[e] - mx); ss += p[e]; }
      float inv = 1.f / ss;
      int i0 = 0;
#pragma unroll
      for (int e = 1; e < NUM_E; ++e) if (p[e] > p[i0]) i0 = e;
      int i1 = (i0 == 0) ? 1 : 0;
#pragma unroll
      for (int e = 0; e < NUM_E; ++e) if (e != i0 && p[e] > p[i1]) i1 = e;
      tok_top[n] = i0 | (i1 << 8);
      tok_wts[n] = make_float2(p[i0] * inv, p[i1] * inv);
    }
  }
}

// gate2: one block per expert; block-wide exclusive scan compacts token lists.
__global__ __launch_bounds__(1024) void gate2_kernel(const int* __restrict__ tok_top,
                                                     const float2* __restrict__ tok_wts,
                                                     int* __restrict__ counts,
                                                     int* __restrict__ tok_idx,
                                                     float* __restrict__ tok_w) {
  const int e = blockIdx.x;
  const int t = threadIdx.x;
  const int lane = t & 63;
  const int wave = t >> 6;
  __shared__ int wsum[16];
  __shared__ int blocktot;
  int match[8];
  float w[8];
  int cnt = 0;
#pragma unroll
  for (int j = 0; j < 8; ++j) {
    int n = t * 8 + j;
    int top = tok_top[n];
    float2 ww = tok_wts[n];
    bool m0 = (top & 0xff) == e;
    bool m1 = ((top >> 8) & 0xff) == e;
    match[j] = (m0 || m1) ? 1 : 0;
    w[j] = m0 ? ww.x : ww.y;
    cnt += match[j];
  }
  int inc = cnt;
#pragma unroll
  for (int off = 1; off < 64; off <<= 1) {
    int v = __shfl_up(inc, off);
    if (lane >= off) inc += v;
  }
  if (lane == 63) wsum[wave] = inc;
  __syncthreads();
  if (t < 16) {
    int v = wsum[t];
    int s = v;
#pragma unroll
    for (int off = 1; off < 16; off <<= 1) {
      int u = __shfl_up(s, off);
      if (lane >= off) s += u;
    }
    wsum[t] = s - v;
    if (t == 15) blocktot = s;
  }
  __syncthreads();
  int slot = wsum[wave] + inc - cnt;
#pragma unroll
  for (int j = 0; j < 8; ++j) {
    if (match[j]) {
      tok_idx[e * N_TOK + slot] = t * 8 + j;
      tok_w[e * N_TOK + slot] = w[j];
      slot++;
    }
  }
  if (t == 0) counts[e] = blocktot;
}

// ---------------- expert GEMMs ----------------
// 128x128 C-tile, BK=64 (two BK=32 LDS planes), single-buffer 2-barrier loop.
// Grid (x=8 experts, y=160 tile-pairs): linear%8 == blockIdx.x == expert ->
// ALL blocks of expert e land on XCD e (restores R4's FETCH 28.8 MB under the
// exact-count mapping; R6's tile table had linear%8 = n-tile -> 146 MB).
// y -> (m_tile = y>>3, n_tile = y&7); early-exit past ceil(count/128) m-tiles
// (y=160 covers 2560 tokens/expert, >12 sigma above binomial mean 2048).
// 4 blocks/CU (LDS 4x33.8KB=135<160KB) to overlap barrier drains.

template <bool FC1>
__global__ __launch_bounds__(256, 4) void moe_gemm_kernel(
    const unsigned short* __restrict__ A_src,  // FC1: x_bf16 ; FC2: h
    const unsigned short* __restrict__ wT,     // [E][1024 n][1024 k] bf16
    const float* __restrict__ bias,            // [E][1024]
    const int* __restrict__ counts,
    const int* __restrict__ tok_idx,           // [E][8192]
    const float* __restrict__ tok_w,           // [E][8192]
    unsigned short* __restrict__ h_out,        // FC1 dest (compacted rows)
    float* __restrict__ out)                   // FC2 dest (atomic accumulate)
{
  const int e = blockIdx.x;                    // linear%8 == e -> XCD e
  const int count = counts[e];
  const int m0 = (blockIdx.y >> 3) * 128;
  if (m0 >= count) return;
  const int n0 = (blockIdx.y & 7) * 128;

  int base = 0;  // 128-padded prefix of counts -> compact h row base (fc1==fc2)
#pragma unroll
  for (int i = 0; i < NUM_E; ++i) base += (i < e) ? ((counts[i] + 127) & ~127) : 0;

  const int tid  = threadIdx.x;
  const int wave = tid >> 6;
  const int lane = tid & 63;
  const int l15  = lane & 15;
  const int quad = lane >> 4;
  const int wm   = wave & 1;
  const int wn   = wave >> 1;

  __shared__ unsigned short sA[2 * 4096];  // [plane][chunk*512 + lane*8]
  __shared__ unsigned short sB[2 * 4096];
  __shared__ int   s_tok[128];
  __shared__ float s_w[128];

  if (!FC1 && tid < 128) {
    int slot = m0 + tid;
    int cs = slot < count ? slot : count - 1;
    s_tok[tid] = tok_idx[e * N_TOK + cs];
    s_w[tid]   = slot < count ? tok_w[e * N_TOK + slot] : 0.f;
  }

  // this lane's two A-staging source rows (chunks 2*wave, 2*wave+1)
  const int r0 = 32 * wave + l15;
  const int r1 = r0 + 16;
  size_t aOff0, aOff1;
  if (FC1) {  // gather token rows from x
    int s0 = m0 + r0; s0 = s0 < count ? s0 : count - 1;
    int s1 = m0 + r1; s1 = s1 < count ? s1 : count - 1;
    aOff0 = (size_t)tok_idx[e * N_TOK + s0] * DIM;
    aOff1 = (size_t)tok_idx[e * N_TOK + s1] * DIM;
  } else {    // contiguous compacted h rows
    aOff0 = (size_t)(base + m0 + r0) * DIM;
    aOff1 = (size_t)(base + m0 + r1) * DIM;
  }
  const unsigned short* wte = wT + (size_t)e * DIM * DIM;
  const size_t bOff0 = (size_t)(n0 + r0) * DIM;
  const size_t bOff1 = (size_t)(n0 + r1) * DIM;
  const int kl = quad * 8;
  const int c0 = (2 * wave + 0) * 512;
  const int c1 = (2 * wave + 1) * 512;

  const f32x4 vzero = {0.f, 0.f, 0.f, 0.f};
  f32x4 acc[4][4];
#pragma unroll
  for (int i = 0; i < 4; ++i)
#pragma unroll
    for (int j = 0; j < 4; ++j) acc[i][j] = vzero;

  for (int k0 = 0; k0 < DIM; k0 += 64) {
    // stage both 32-wide planes of the 64-wide K-tile (8 async16/lane)
    async16(A_src + aOff0 + k0 + kl,      &sA[c0]);
    async16(A_src + aOff1 + k0 + kl,      &sA[c1]);
    async16(A_src + aOff0 + k0 + 32 + kl, &sA[4096 + c0]);
    async16(A_src + aOff1 + k0 + 32 + kl, &sA[4096 + c1]);
    async16(wte + bOff0 + k0 + kl,        &sB[c0]);
    async16(wte + bOff1 + k0 + kl,        &sB[c1]);
    async16(wte + bOff0 + k0 + 32 + kl,   &sB[4096 + c0]);
    async16(wte + bOff1 + k0 + 32 + kl,   &sB[4096 + c1]);
    __syncthreads();  // vmcnt(0) drain + barrier (L2-class latency now)
#pragma unroll
    for (int s = 0; s < 2; ++s) {
      short8 af[4], bfr[4];
#pragma unroll
      for (int i = 0; i < 4; ++i)
        af[i] = *(const short8*)&sA[s * 4096 + (wm * 4 + i) * 512 + lane * 8];
#pragma unroll
      for (int j = 0; j < 4; ++j)
        bfr[j] = *(const short8*)&sB[s * 4096 + (wn * 4 + j) * 512 + lane * 8];
#pragma unroll
      for (int i = 0; i < 4; ++i)
#pragma unroll
        for (int j = 0; j < 4; ++j)
          acc[i][j] = __builtin_amdgcn_mfma_f32_16x16x32_bf16(af[i], bfr[j], acc[i][j], 0, 0, 0);
    }
    __syncthreads();  // WAR guard before next stage overwrites
  }

  float bv[4];
#pragma unroll
  for (int j = 0; j < 4; ++j)
    bv[j] = bias[e * DIM + n0 + (wn * 4 + j) * 16 + l15];

  // C/D layout (m89-verified): col = lane&15, row = quad*4 + reg
  if (FC1) {
#pragma unroll
    for (int i = 0; i < 4; ++i) {
      const int rbase = (wm * 4 + i) * 16 + quad * 4;
#pragma unroll
      for (int r = 0; r < 4; ++r) {
        const int slot = m0 + rbase + r;
        if (slot < count) {
          unsigned short* hp = h_out + (size_t)(base + slot) * DIM + n0;
#pragma unroll
          for (int j = 0; j < 4; ++j) {
            float v = acc[i][j][r] + bv[j];
            v = v > 0.f ? v : 0.f;
            hp[(wn * 4 + j) * 16 + l15] = f2bf(v);
          }
        }
      }
    }
  } else {
#pragma unroll
    for (int i = 0; i < 4; ++i) {
      const int rbase = (wm * 4 + i) * 16 + quad * 4;
#pragma unroll
      for (int r = 0; r < 4; ++r) {
        const int slot = m0 + rbase + r;
        if (slot < count) {
          const int rl = rbase + r;
          const int tok = s_tok[rl];
          const float w = s_w[rl];
          float* op = out + (size_t)tok * DIM + n0;
#pragma unroll
          for (int j = 0; j < 4; ++j) {
            float v = acc[i][j][r] + bv[j];
            atomicAdd(&op[(wn * 4 + j) * 16 + l15], w * v);
          }
        }
      }
    }
  }
}

// ---------------- launch ----------------
// ws layout (bytes):
//   0        counts[8]
//   1024     tok_idx [8][8192] int    (256 KB)
//   263168   tok_w   [8][8192] float  (256 KB)
//   525312   x_bf16  [8192][1024]     (16 MB)
//   +16MB    W1T bf16 [8][1024][1024] (16 MB)
//   +32MB    W2T bf16                 (16 MB)
//   +48MB    h bf16, 17408 rows x1024 (34 MB)  (sum padded counts <= 17400)
//   +~82.5MB tok_top int[8192] (32KB), tok_wts float2[8192] (64KB)

extern "C" void kernel_launch(void* const* d_in, const int* in_sizes, int n_in,
                              void* d_out, int out_size, void* d_ws, size_t ws_size,
                              hipStream_t stream) {
  const float* x  = (const float*)d_in[0];
  const float* W1 = (const float*)d_in[1];
  const float* b1 = (const float*)d_in[2];
  const float* W2 = (const float*)d_in[3];
  const float* b2 = (const float*)d_in[4];
  const float* Wg = (const float*)d_in[5];
  const float* bg = (const float*)d_in[6];
  float* out = (float*)d_out;

  char* ws = (char*)d_ws;
  int*            counts  = (int*)(ws);
  int*            tok_idx = (int*)(ws + 1024);
  float*          tok_w   = (float*)(ws + 263168);
  unsigned short* xb      = (unsigned short*)(ws + 525312);
  unsigned short* w1t     = (unsigned short*)(ws + 525312 + 16777216ull);
  unsigned short* w2t     = (unsigned short*)(ws + 525312 + 2ull * 16777216ull);
  unsigned short* hb      = (unsigned short*)(ws + 525312 + 3ull * 16777216ull);
  size_t gate_off = 525312 + 3ull * 16777216ull + 35651584ull;
  int*            tok_top = (int*)(ws + gate_off);
  float2*         tok_wts = (float2*)(ws + gate_off + 32768);

  hipMemsetAsync(d_out, 0, (size_t)N_TOK * DIM * sizeof(float), stream);

  prep_kernel<<<4096 + 2048, 256, 0, stream>>>(W1, W2, w1t, w2t,
                                               x, Wg, bg, tok_top, tok_wts, xb);
  gate2_kernel<<<NUM_E, 1024, 0, stream>>>(tok_top, tok_wts, counts, tok_idx, tok_w);
  // x = expert (XCD-clustered), y = (m_tile<<3)|n_tile
  moe_gemm_kernel<true><<<dim3(8, 160), 256, 0, stream>>>(
      xb, w1t, b1, counts, tok_idx, tok_w, hb, nullptr);
  moe_gemm_kernel<false><<<dim3(8, 160), 256, 0, stream>>>(
      hb, w2t, b2, counts, tok_idx, tok_w, nullptr, out);
}